// Round 6
// baseline (111.757 us; speedup 1.0000x reference)
//
#include <hip/hip_runtime.h>
#include <math.h>

// Problem geometry (fixed by the reference): B=32, C=1, H=W=1024.
#define NB 32
#define PER_BATCH (1024 * 1024)          // elements per batch row (C*H*W)
#define BLOCKS_PER_BATCH 64
#define THREADS 256
#define NBLOCKS (NB * BLOCKS_PER_BATCH)                  // 2048
#define ELEMS_PER_BLOCK (PER_BATCH / BLOCKS_PER_BATCH)   // 16384
#define V4_PER_BLOCK (ELEMS_PER_BLOCK / 4)               // 4096
#define V4_PER_THREAD (V4_PER_BLOCK / THREADS)           // 16 stages of 1 pair

typedef __attribute__((ext_vector_type(4))) float f32x4;

// ws layout: float4 partials[NBLOCKS] = {bce, ps, pts, ts} per block,
//            then int done_counter (memset to 0 each launch).

// Opaque asm loads: compiler cannot sink/collapse them and inserts no vmcnt
// drains. Depth-6 rotating pipeline, 2 loads/stage -> steady wait vmcnt(10)
// (12 loads in flight, wait for the oldest pair only).
#define LOADP(XB, TB, K)                                                      \
    {                                                                         \
        const uint32_t vo = base_off + (uint32_t)((K) * THREADS * 16);        \
        asm volatile("global_load_dwordx4 %0, %2, %3\n\t"                     \
                     "global_load_dwordx4 %1, %2, %4"                         \
                     : "=&v"(XB), "=&v"(TB)                                   \
                     : "v"(vo), "s"(x4), "s"(t4));                            \
    }

#define WAITV(N)                                                              \
    asm volatile("s_waitcnt vmcnt(" #N ")" ::: "memory");                     \
    __builtin_amdgcn_sched_barrier(0);

#define COMP1(XB, TB)                                              \
    _Pragma("unroll")                                              \
    for (int j = 0; j < 4; ++j) {                                  \
        const float x = XB[j];                                     \
        const float t = TB[j];                                     \
        const float e = __expf(-fabsf(x));                         \
        const float ope = 1.0f + e;                                \
        const float inv = __builtin_amdgcn_rcpf(ope);              \
        const float p = (x >= 0.f) ? inv : 1.0f - inv;             \
        const float lg = __logf(ope);                              \
        if (j & 1) {                                               \
            bce1 += __builtin_fmaf(-x, t, fmaxf(x, 0.f) + lg);     \
            ps1 += p;                                              \
            pts1 = __builtin_fmaf(p, t, pts1);                     \
            ts1 += t;                                              \
        } else {                                                   \
            bce0 += __builtin_fmaf(-x, t, fmaxf(x, 0.f) + lg);     \
            ps0 += p;                                              \
            pts0 = __builtin_fmaf(p, t, pts0);                     \
            ts0 += t;                                              \
        }                                                          \
    }

__global__ __launch_bounds__(THREADS) void
loss_fused(const float4* __restrict__ x4p, const float4* __restrict__ t4p,
           float4* __restrict__ partials, int* __restrict__ done,
           float* __restrict__ out) {
    const int blk = blockIdx.x;
    const int batch = blk / BLOCKS_PER_BATCH;
    const int bblk = blk % BLOCKS_PER_BATCH;
    const float* x4 = (const float*)x4p;   // SGPR base for asm loads
    const float* t4 = (const float*)t4p;
    const uint32_t base_off =
        (uint32_t)(((size_t)batch * (PER_BATCH / 4) +
                    (size_t)bblk * V4_PER_BLOCK + threadIdx.x) * 16u);

    float bce0 = 0.f, bce1 = 0.f;
    float ps0 = 0.f, ps1 = 0.f;
    float pts0 = 0.f, pts1 = 0.f;
    float ts0 = 0.f, ts1 = 0.f;

    f32x4 xa, ta, xb, tb, xc, tc, xd, td, xe, te, xf, tf;
    // Prologue: fill the 6-deep pipeline (12 loads in flight).
    LOADP(xa, ta, 0)
    LOADP(xb, tb, 1)
    LOADP(xc, tc, 2)
    LOADP(xd, td, 3)
    LOADP(xe, te, 4)
    LOADP(xf, tf, 5)
    // Steady state: wait only for the oldest pair, compute, refill.
    WAITV(10)  COMP1(xa, ta)  LOADP(xa, ta, 6)
    WAITV(10)  COMP1(xb, tb)  LOADP(xb, tb, 7)
    WAITV(10)  COMP1(xc, tc)  LOADP(xc, tc, 8)
    WAITV(10)  COMP1(xd, td)  LOADP(xd, td, 9)
    WAITV(10)  COMP1(xe, te)  LOADP(xe, te, 10)
    WAITV(10)  COMP1(xf, tf)  LOADP(xf, tf, 11)
    WAITV(10)  COMP1(xa, ta)  LOADP(xa, ta, 12)
    WAITV(10)  COMP1(xb, tb)  LOADP(xb, tb, 13)
    WAITV(10)  COMP1(xc, tc)  LOADP(xc, tc, 14)
    WAITV(10)  COMP1(xd, td)  LOADP(xd, td, 15)
    // Epilogue: drain 10 -> 8 -> 6 -> 4 -> 2 -> 0.
    WAITV(10)  COMP1(xe, te)
    WAITV(8)   COMP1(xf, tf)
    WAITV(6)   COMP1(xa, ta)
    WAITV(4)   COMP1(xb, tb)
    WAITV(2)   COMP1(xc, tc)
    WAITV(0)   COMP1(xd, td)

    float bce = bce0 + bce1;
    float ps = ps0 + ps1;
    float pts = pts0 + pts1;
    float ts = ts0 + ts1;

    // Wave (64-lane) butterfly reduce of the 4 partials.
    for (int off = 32; off > 0; off >>= 1) {
        bce += __shfl_down(bce, off);
        ps  += __shfl_down(ps, off);
        pts += __shfl_down(pts, off);
        ts  += __shfl_down(ts, off);
    }

    __shared__ float red[4][4];   // [wave][value]
    __shared__ int lastFlag;
    const int lane = threadIdx.x & 63;
    const int wave = threadIdx.x >> 6;
    if (lane == 0) {
        red[wave][0] = bce; red[wave][1] = ps;
        red[wave][2] = pts; red[wave][3] = ts;
    }
    __syncthreads();
    if (threadIdx.x == 0) {
        for (int w = 1; w < 4; ++w) {
            bce += red[w][0]; ps += red[w][1];
            pts += red[w][2]; ts += red[w][3];
        }
        partials[blk] = make_float4(bce, ps, pts, ts);
        __threadfence();                      // publish partial (device scope)
        const int old = atomicAdd(done, 1);   // device-scope RMW
        lastFlag = (old == NBLOCKS - 1);
    }
    __syncthreads();

    // Last-arriving block finalizes: 2048 float4 = 32 KB, L2/L3-resident.
    if (lastFlag) {
        __threadfence();                      // acquire published partials
        // Thread i reads blocks 8i..8i+7 (all within batch i/8).
        float bce_l = 0.f, ps_l = 0.f, pts_l = 0.f, ts_l = 0.f;
        const int t8 = threadIdx.x * 8;
#pragma unroll
        for (int j = 0; j < 8; ++j) {
            const float4 v = partials[t8 + j];
            bce_l += v.x; ps_l += v.y; pts_l += v.z; ts_l += v.w;
        }
        // 8-lane-group butterfly: every lane gets its group's (=batch's) sums.
        for (int off = 1; off < 8; off <<= 1) {
            bce_l += __shfl_xor(bce_l, off);
            ps_l  += __shfl_xor(ps_l, off);
            pts_l += __shfl_xor(pts_l, off);
            ts_l  += __shfl_xor(ts_l, off);
        }
        __shared__ float sps[NB], spts[NB], sts[NB], sbce[NB];
        if ((threadIdx.x & 7) == 0) {
            const int b = threadIdx.x >> 3;   // batch 0..31
            sps[b] = ps_l; spts[b] = pts_l; sts[b] = ts_l; sbce[b] = bce_l;
        }
        __syncthreads();
        if (threadIdx.x < 64) {
            float coef = 0.f, bsum = 0.f;
            if (threadIdx.x < NB) {
                coef = (2.0f * spts[threadIdx.x] + 1e-5f) /
                       (sps[threadIdx.x] + sts[threadIdx.x] + 1e-5f);
                bsum = sbce[threadIdx.x];
            }
            for (int off = 32; off > 0; off >>= 1) {
                coef += __shfl_down(coef, off);
                bsum += __shfl_down(bsum, off);
            }
            if (threadIdx.x == 0) {
                const double n = (double)NB * (double)PER_BATCH;
                // csd_loss is identically 0 (dt_map is zeros_like).
                out[0] = (float)((double)bsum / n) + 1.0f - coef / (float)NB;
            }
        }
    }
}

extern "C" void kernel_launch(void* const* d_in, const int* in_sizes, int n_in,
                              void* d_out, int out_size, void* d_ws, size_t ws_size,
                              hipStream_t stream) {
    const float4* x4 = (const float4*)d_in[0];
    const float4* t4 = (const float4*)d_in[1];
    float4* partials = (float4*)d_ws;                    // 32 KB, rewritten
    int* done = (int*)((char*)d_ws + NBLOCKS * sizeof(float4));
    float* out = (float*)d_out;

    hipMemsetAsync(done, 0, sizeof(int), stream);
    loss_fused<<<NBLOCKS, THREADS, 0, stream>>>(x4, t4, partials, done, out);
}

// Round 7
// 57.035 us; speedup vs baseline: 1.9595x; 1.9595x over previous
//
#include <hip/hip_runtime.h>
#include <math.h>

// Problem geometry (fixed by the reference): B=32, C=1, H=W=1024.
#define NB 32
#define PER_BATCH (1024 * 1024)          // elements per batch row (C*H*W)
#define BLOCKS_PER_BATCH 64
#define THREADS 256
#define NBLOCKS (NB * BLOCKS_PER_BATCH)                  // 2048
#define ELEMS_PER_BLOCK (PER_BATCH / BLOCKS_PER_BATCH)   // 16384
#define V4_PER_BLOCK (ELEMS_PER_BLOCK / 4)               // 4096
#define V4_PER_THREAD (V4_PER_BLOCK / THREADS)           // 16 stages of 1 pair

typedef __attribute__((ext_vector_type(4))) float f32x4;

// ws layout: float4 partials[NBLOCKS] = {bce, ps, pts, ts} per block.

// Opaque asm loads with hand-counted vmcnt (depth-6, steady wait vmcnt(10)).
// Cache-policy steering: x (input) is loaded with default policy so its
// 128 MB becomes Infinity-Cache-resident; t (target) is loaded `nt`
// (non-temporal, no L2/IC allocation) so it streams from HBM without
// evicting x. Working set == IC size, so without steering both streams
// thrash the IC at ~50% residency.
#define LOADP(XB, TB, K)                                                      \
    {                                                                         \
        const uint32_t vo = base_off + (uint32_t)((K) * THREADS * 16);        \
        asm volatile("global_load_dwordx4 %0, %2, %3\n\t"                     \
                     "global_load_dwordx4 %1, %2, %4 nt"                      \
                     : "=&v"(XB), "=&v"(TB)                                   \
                     : "v"(vo), "s"(x4), "s"(t4));                            \
    }

#define WAITV(N)                                                              \
    asm volatile("s_waitcnt vmcnt(" #N ")" ::: "memory");                     \
    __builtin_amdgcn_sched_barrier(0);

#define COMP1(XB, TB)                                              \
    _Pragma("unroll")                                              \
    for (int j = 0; j < 4; ++j) {                                  \
        const float x = XB[j];                                     \
        const float t = TB[j];                                     \
        const float e = __expf(-fabsf(x));                         \
        const float ope = 1.0f + e;                                \
        const float inv = __builtin_amdgcn_rcpf(ope);              \
        const float p = (x >= 0.f) ? inv : 1.0f - inv;             \
        const float lg = __logf(ope);                              \
        if (j & 1) {                                               \
            bce1 += __builtin_fmaf(-x, t, fmaxf(x, 0.f) + lg);     \
            ps1 += p;                                              \
            pts1 = __builtin_fmaf(p, t, pts1);                     \
            ts1 += t;                                              \
        } else {                                                   \
            bce0 += __builtin_fmaf(-x, t, fmaxf(x, 0.f) + lg);     \
            ps0 += p;                                              \
            pts0 = __builtin_fmaf(p, t, pts0);                     \
            ts0 += t;                                              \
        }                                                          \
    }

__global__ __launch_bounds__(THREADS) void
loss_pass1(const float4* __restrict__ x4p, const float4* __restrict__ t4p,
           float4* __restrict__ partials) {
    const int blk = blockIdx.x;
    const int batch = blk / BLOCKS_PER_BATCH;
    const int bblk = blk % BLOCKS_PER_BATCH;
    const float* x4 = (const float*)x4p;   // SGPR base for asm loads
    const float* t4 = (const float*)t4p;
    const uint32_t base_off =
        (uint32_t)(((size_t)batch * (PER_BATCH / 4) +
                    (size_t)bblk * V4_PER_BLOCK + threadIdx.x) * 16u);

    float bce0 = 0.f, bce1 = 0.f;
    float ps0 = 0.f, ps1 = 0.f;
    float pts0 = 0.f, pts1 = 0.f;
    float ts0 = 0.f, ts1 = 0.f;

    f32x4 xa, ta, xb, tb, xc, tc, xd, td, xe, te, xf, tf;
    // Prologue: fill the 6-deep pipeline (12 loads in flight).
    LOADP(xa, ta, 0)
    LOADP(xb, tb, 1)
    LOADP(xc, tc, 2)
    LOADP(xd, td, 3)
    LOADP(xe, te, 4)
    LOADP(xf, tf, 5)
    // Steady state: wait only for the oldest pair, compute, refill.
    WAITV(10)  COMP1(xa, ta)  LOADP(xa, ta, 6)
    WAITV(10)  COMP1(xb, tb)  LOADP(xb, tb, 7)
    WAITV(10)  COMP1(xc, tc)  LOADP(xc, tc, 8)
    WAITV(10)  COMP1(xd, td)  LOADP(xd, td, 9)
    WAITV(10)  COMP1(xe, te)  LOADP(xe, te, 10)
    WAITV(10)  COMP1(xf, tf)  LOADP(xf, tf, 11)
    WAITV(10)  COMP1(xa, ta)  LOADP(xa, ta, 12)
    WAITV(10)  COMP1(xb, tb)  LOADP(xb, tb, 13)
    WAITV(10)  COMP1(xc, tc)  LOADP(xc, tc, 14)
    WAITV(10)  COMP1(xd, td)  LOADP(xd, td, 15)
    // Epilogue: drain 10 -> 8 -> 6 -> 4 -> 2 -> 0.
    WAITV(10)  COMP1(xe, te)
    WAITV(8)   COMP1(xf, tf)
    WAITV(6)   COMP1(xa, ta)
    WAITV(4)   COMP1(xb, tb)
    WAITV(2)   COMP1(xc, tc)
    WAITV(0)   COMP1(xd, td)

    float bce = bce0 + bce1;
    float ps = ps0 + ps1;
    float pts = pts0 + pts1;
    float ts = ts0 + ts1;

    // Wave (64-lane) butterfly reduce of the 4 partials.
    for (int off = 32; off > 0; off >>= 1) {
        bce += __shfl_down(bce, off);
        ps  += __shfl_down(ps, off);
        pts += __shfl_down(pts, off);
        ts  += __shfl_down(ts, off);
    }

    __shared__ float red[4][4];   // [wave][value]
    const int lane = threadIdx.x & 63;
    const int wave = threadIdx.x >> 6;
    if (lane == 0) {
        red[wave][0] = bce; red[wave][1] = ps;
        red[wave][2] = pts; red[wave][3] = ts;
    }
    __syncthreads();
    if (threadIdx.x == 0) {
        for (int w = 1; w < 4; ++w) {
            bce += red[w][0]; ps += red[w][1];
            pts += red[w][2]; ts += red[w][3];
        }
        partials[blk] = make_float4(bce, ps, pts, ts);  // no atomics
    }
}

__global__ __launch_bounds__(1024) void
loss_final(const float4* __restrict__ partials, float* __restrict__ out) {
    __shared__ float sps[NB], spts[NB], sts[NB];
    __shared__ float sbce[16];
    const int i = threadIdx.x;          // 1024 threads = 16 waves
    const int lane = i & 63;
    const int wave = i >> 6;

    if (i < NB) { sps[i] = 0.f; spts[i] = 0.f; sts[i] = 0.f; }
    __syncthreads();

    const float4 a = partials[i];
    const float4 b = partials[i + 1024];
    float bce = a.x + b.x;
    const int batchA = i >> 6;            // blocks 0..1023    -> batches 0..15
    const int batchB = (i + 1024) >> 6;   // blocks 1024..2047 -> batches 16..31
    atomicAdd(&sps[batchA], a.y); atomicAdd(&spts[batchA], a.z); atomicAdd(&sts[batchA], a.w);
    atomicAdd(&sps[batchB], b.y); atomicAdd(&spts[batchB], b.z); atomicAdd(&sts[batchB], b.w);

    for (int off = 32; off > 0; off >>= 1) bce += __shfl_down(bce, off);
    if (lane == 0) sbce[wave] = bce;
    __syncthreads();

    if (i < 64) {
        float coef = 0.f;
        if (i < NB) coef = (2.0f * spts[i] + 1e-5f) / (sps[i] + sts[i] + 1e-5f);
        for (int off = 32; off > 0; off >>= 1) coef += __shfl_down(coef, off);
        if (i == 0) {
            float bt = 0.f;
            for (int w = 0; w < 16; ++w) bt += sbce[w];
            const double n = (double)NB * (double)PER_BATCH;
            // csd_loss is identically 0 (dt_map is zeros_like).
            out[0] = (float)((double)bt / n) + 1.0f - coef / (float)NB;
        }
    }
}

extern "C" void kernel_launch(void* const* d_in, const int* in_sizes, int n_in,
                              void* d_out, int out_size, void* d_ws, size_t ws_size,
                              hipStream_t stream) {
    const float4* x4 = (const float4*)d_in[0];
    const float4* t4 = (const float4*)d_in[1];
    float4* partials = (float4*)d_ws;     // NBLOCKS float4 = 32 KB, fully
    float* out = (float*)d_out;           // rewritten every launch

    loss_pass1<<<NBLOCKS, THREADS, 0, stream>>>(x4, t4, partials);
    loss_final<<<1, 1024, 0, stream>>>(partials, out);
}

// Round 8
// 47.391 us; speedup vs baseline: 2.3582x; 1.2035x over previous
//
#include <hip/hip_runtime.h>
#include <math.h>

// Problem geometry (fixed by the reference): B=32, C=1, H=W=1024.
#define NB 32
#define PER_BATCH (1024 * 1024)          // elements per batch row (C*H*W)
#define BLOCKS_PER_BATCH 64
#define THREADS 256
#define NBLOCKS (NB * BLOCKS_PER_BATCH)                  // 2048
#define ELEMS_PER_BLOCK (PER_BATCH / BLOCKS_PER_BATCH)   // 16384
#define V4_PER_BLOCK (ELEMS_PER_BLOCK / 4)               // 4096
#define V4_PER_THREAD (V4_PER_BLOCK / THREADS)           // 16 stages of 1 pair

typedef __attribute__((ext_vector_type(4))) float f32x4;

// ws layout: float4 partials[NBLOCKS] = {bce, ps, pts, ts} per block.

// Opaque asm loads with hand-counted vmcnt (depth-6, steady wait vmcnt(10)).
// Cache policy: x cached (Infinity-Cache-resident across replays), t `nt`
// (streams from HBM, no IC eviction pressure).
#define LOADP(XB, TB, K)                                                      \
    {                                                                         \
        const uint32_t vo = base_off + (uint32_t)((K) * THREADS * 16);        \
        asm volatile("global_load_dwordx4 %0, %2, %3\n\t"                     \
                     "global_load_dwordx4 %1, %2, %4 nt"                      \
                     : "=&v"(XB), "=&v"(TB)                                   \
                     : "v"(vo), "s"(x4), "s"(t4));                            \
    }

#define WAITV(N)                                                              \
    asm volatile("s_waitcnt vmcnt(" #N ")" ::: "memory");                     \
    __builtin_amdgcn_sched_barrier(0);

#define COMP1(XB, TB)                                              \
    _Pragma("unroll")                                              \
    for (int j = 0; j < 4; ++j) {                                  \
        const float x = XB[j];                                     \
        const float t = TB[j];                                     \
        const float e = __expf(-fabsf(x));                         \
        const float ope = 1.0f + e;                                \
        const float inv = __builtin_amdgcn_rcpf(ope);              \
        const float p = (x >= 0.f) ? inv : 1.0f - inv;             \
        const float lg = __logf(ope);                              \
        if (j & 1) {                                               \
            bce1 += __builtin_fmaf(-x, t, fmaxf(x, 0.f) + lg);     \
            ps1 += p;                                              \
            pts1 = __builtin_fmaf(p, t, pts1);                     \
            ts1 += t;                                              \
        } else {                                                   \
            bce0 += __builtin_fmaf(-x, t, fmaxf(x, 0.f) + lg);     \
            ps0 += p;                                              \
            pts0 = __builtin_fmaf(p, t, pts0);                     \
            ts0 += t;                                              \
        }                                                          \
    }

__global__ __launch_bounds__(THREADS) void
loss_pass1(const float4* __restrict__ x4p, const float4* __restrict__ t4p,
           float4* __restrict__ partials) {
    const int blk = blockIdx.x;
    const int batch = blk / BLOCKS_PER_BATCH;
    const int bblk = blk % BLOCKS_PER_BATCH;
    const float* x4 = (const float*)x4p;   // SGPR base for asm loads
    const float* t4 = (const float*)t4p;
    const uint32_t base_off =
        (uint32_t)(((size_t)batch * (PER_BATCH / 4) +
                    (size_t)bblk * V4_PER_BLOCK + threadIdx.x) * 16u);

    float bce0 = 0.f, bce1 = 0.f;
    float ps0 = 0.f, ps1 = 0.f;
    float pts0 = 0.f, pts1 = 0.f;
    float ts0 = 0.f, ts1 = 0.f;

    f32x4 xa, ta, xb, tb, xc, tc, xd, td, xe, te, xf, tf;
    // Prologue: fill the 6-deep pipeline (12 loads in flight).
    LOADP(xa, ta, 0)
    LOADP(xb, tb, 1)
    LOADP(xc, tc, 2)
    LOADP(xd, td, 3)
    LOADP(xe, te, 4)
    LOADP(xf, tf, 5)
    // Steady state: wait only for the oldest pair, compute, refill.
    WAITV(10)  COMP1(xa, ta)  LOADP(xa, ta, 6)
    WAITV(10)  COMP1(xb, tb)  LOADP(xb, tb, 7)
    WAITV(10)  COMP1(xc, tc)  LOADP(xc, tc, 8)
    WAITV(10)  COMP1(xd, td)  LOADP(xd, td, 9)
    WAITV(10)  COMP1(xe, te)  LOADP(xe, te, 10)
    WAITV(10)  COMP1(xf, tf)  LOADP(xf, tf, 11)
    WAITV(10)  COMP1(xa, ta)  LOADP(xa, ta, 12)
    WAITV(10)  COMP1(xb, tb)  LOADP(xb, tb, 13)
    WAITV(10)  COMP1(xc, tc)  LOADP(xc, tc, 14)
    WAITV(10)  COMP1(xd, td)  LOADP(xd, td, 15)
    // Epilogue: drain 10 -> 8 -> 6 -> 4 -> 2 -> 0.
    WAITV(10)  COMP1(xe, te)
    WAITV(8)   COMP1(xf, tf)
    WAITV(6)   COMP1(xa, ta)
    WAITV(4)   COMP1(xb, tb)
    WAITV(2)   COMP1(xc, tc)
    WAITV(0)   COMP1(xd, td)

    float bce = bce0 + bce1;
    float ps = ps0 + ps1;
    float pts = pts0 + pts1;
    float ts = ts0 + ts1;

    // Wave (64-lane) butterfly reduce of the 4 partials.
    for (int off = 32; off > 0; off >>= 1) {
        bce += __shfl_down(bce, off);
        ps  += __shfl_down(ps, off);
        pts += __shfl_down(pts, off);
        ts  += __shfl_down(ts, off);
    }

    __shared__ float red[4][4];   // [wave][value]
    const int lane = threadIdx.x & 63;
    const int wave = threadIdx.x >> 6;
    if (lane == 0) {
        red[wave][0] = bce; red[wave][1] = ps;
        red[wave][2] = pts; red[wave][3] = ts;
    }
    __syncthreads();
    if (threadIdx.x == 0) {
        for (int w = 1; w < 4; ++w) {
            bce += red[w][0]; ps += red[w][1];
            pts += red[w][2]; ts += red[w][3];
        }
        partials[blk] = make_float4(bce, ps, pts, ts);  // no atomics
    }
}

// Slim finalizer: 1 block x 256 threads, thread i reads blocks 8i..8i+7
// (all within batch i/8; partials are L2-hot, 32 KB total).
__global__ __launch_bounds__(256) void
loss_final(const float4* __restrict__ partials, float* __restrict__ out) {
    const int i = threadIdx.x;
    float bce = 0.f, ps = 0.f, pts = 0.f, ts = 0.f;
    const int t8 = i * 8;
#pragma unroll
    for (int j = 0; j < 8; ++j) {
        const float4 v = partials[t8 + j];
        bce += v.x; ps += v.y; pts += v.z; ts += v.w;
    }
    // 8-lane-group butterfly: each group of 8 threads covers one batch.
    for (int off = 1; off < 8; off <<= 1) {
        bce += __shfl_xor(bce, off);
        ps  += __shfl_xor(ps, off);
        pts += __shfl_xor(pts, off);
        ts  += __shfl_xor(ts, off);
    }
    __shared__ float sbce[NB], sps[NB], spts[NB], sts[NB];
    if ((i & 7) == 0) {
        const int b = i >> 3;   // batch 0..31
        sbce[b] = bce; sps[b] = ps; spts[b] = pts; sts[b] = ts;
    }
    __syncthreads();
    if (i < 64) {
        float coef = 0.f, bsum = 0.f;
        if (i < NB) {
            coef = (2.0f * spts[i] + 1e-5f) / (sps[i] + sts[i] + 1e-5f);
            bsum = sbce[i];
        }
        for (int off = 32; off > 0; off >>= 1) {
            coef += __shfl_down(coef, off);
            bsum += __shfl_down(bsum, off);
        }
        if (i == 0) {
            const double n = (double)NB * (double)PER_BATCH;
            // csd_loss is identically 0 (dt_map is zeros_like).
            out[0] = (float)((double)bsum / n) + 1.0f - coef / (float)NB;
        }
    }
}

extern "C" void kernel_launch(void* const* d_in, const int* in_sizes, int n_in,
                              void* d_out, int out_size, void* d_ws, size_t ws_size,
                              hipStream_t stream) {
    const float4* x4 = (const float4*)d_in[0];
    const float4* t4 = (const float4*)d_in[1];
    float4* partials = (float4*)d_ws;     // NBLOCKS float4 = 32 KB, fully
    float* out = (float*)d_out;           // rewritten every launch

    loss_pass1<<<NBLOCKS, THREADS, 0, stream>>>(x4, t4, partials);
    loss_final<<<1, 256, 0, stream>>>(partials, out);
}